// Round 14
// baseline (367.184 us; speedup 1.0000x reference)
//
#include <hip/hip_runtime.h>
#include <hip/hip_bf16.h>
#include <math.h>
#include <stdint.h>

#define B_  256
#define N_  1024
#define D_  512
#define H_  2048
#define O_  512
#define M4  (4 * B_)
#define M12 (12 * B_)
#define NCH 8

typedef __attribute__((ext_vector_type(8))) short short8;
typedef __attribute__((ext_vector_type(4))) float f32x4;
typedef unsigned short ushort_t;

__device__ inline uint32_t pkbf(float a, float b) {
    union { __hip_bfloat162 h; uint32_t u; } cv;
    cv.h = __float22bfloat162_rn(float2{a, b});
    return cv.u;
}
__device__ inline ushort_t f2bf(float f) {
    union { float f; uint32_t u; } v; v.f = f;
    uint32_t r = v.u + 0x7FFFu + ((v.u >> 16) & 1u);
    return (ushort_t)(r >> 16);
}

__device__ inline void load_lds16(const void* g, void* l) {
    typedef const __attribute__((address_space(1))) uint32_t* gp_t;
    typedef __attribute__((address_space(3))) uint32_t* lp_t;
    __builtin_amdgcn_global_load_lds((gp_t)(uintptr_t)g, (lp_t)(uint32_t)(uintptr_t)l,
                                     16, 0, 0);
}

// ---------------------------------------------------------------------------
// agg core: per (b, n-chunk) partials. NT loads, unroll 8.
// ---------------------------------------------------------------------------
__device__ __forceinline__ void agg_core(const float* __restrict__ x,
                                         const float* __restrict__ mask,
                                         float* __restrict__ part,
                                         float* __restrict__ cntp,
                                         int id, int t) {
    const int b    = id >> 2;
    const int c    = id & 3;
    const int half = t >> 7;
    const int d4   = (t & 127) << 2;
    const float* base = x + ((size_t)b * N_ + (size_t)c * 256) * D_ + d4;
    const float* mp   = mask + (size_t)b * N_ + (size_t)c * 256;

    f32x4 sum = {0.f,0.f,0.f,0.f}, sq = {0.f,0.f,0.f,0.f};
    f32x4 mx = {-INFINITY,-INFINITY,-INFINITY,-INFINITY};
    f32x4 mn = { INFINITY, INFINITY, INFINITY, INFINITY};
    float cnt = 0.f;

    #pragma unroll 8
    for (int n = half; n < 256; n += 2) {
        float m = mp[n];
        f32x4 v = __builtin_nontemporal_load((const f32x4*)(base + (size_t)n * D_));
        sum.x = fmaf(v.x, m, sum.x); sum.y = fmaf(v.y, m, sum.y);
        sum.z = fmaf(v.z, m, sum.z); sum.w = fmaf(v.w, m, sum.w);
        sq.x  = fmaf(v.x * v.x, m, sq.x); sq.y = fmaf(v.y * v.y, m, sq.y);
        sq.z  = fmaf(v.z * v.z, m, sq.z); sq.w = fmaf(v.w * v.w, m, sq.w);
        cnt  += m;
        bool um = m > 0.f;
        mx.x = um ? fmaxf(mx.x, v.x) : mx.x; mx.y = um ? fmaxf(mx.y, v.y) : mx.y;
        mx.z = um ? fmaxf(mx.z, v.z) : mx.z; mx.w = um ? fmaxf(mx.w, v.w) : mx.w;
        mn.x = um ? fminf(mn.x, v.x) : mn.x; mn.y = um ? fminf(mn.y, v.y) : mn.y;
        mn.z = um ? fminf(mn.z, v.z) : mn.z; mn.w = um ? fminf(mn.w, v.w) : mn.w;
    }

    const int ch = c * 2 + half;
    const size_t SS = (size_t)B_ * NCH * D_;
    const size_t pi = ((size_t)(b * NCH + ch)) * D_ + d4;
    *(f32x4*)(part + 0 * SS + pi) = sum;
    *(f32x4*)(part + 1 * SS + pi) = sq;
    *(f32x4*)(part + 2 * SS + pi) = mx;
    *(f32x4*)(part + 3 * SS + pi) = mn;
    if ((t & 127) == 0) cntp[b * NCH + ch] = cnt;
}

// ---------------------------------------------------------------------------
// K1 mega-kernel: agg partials + last-block finalize [0,1024) |
//                 W1 conv [1024,2048) | W2 conv [2048,3072) | scales 3072
// ---------------------------------------------------------------------------
__device__ void conv_tile(const float* __restrict__ in, ushort_t* __restrict__ out,
                          int R, int C, int bx, int by, float* tile) {
    const int t  = threadIdx.x;
    const int r0 = by << 5;
    const int c0 = bx << 5;
    const int tr = t >> 3;
    const int tc = (t & 7) << 2;

    float4 v = *(const float4*)(in + (size_t)(r0 + tr) * C + c0 + tc);
    tile[tr * 33 + tc + 0] = v.x; tile[tr * 33 + tc + 1] = v.y;
    tile[tr * 33 + tc + 2] = v.z; tile[tr * 33 + tc + 3] = v.w;
    __syncthreads();

    union { uint32_t u[2]; ushort4 us; } o;
    o.u[0] = pkbf(tile[(tc + 0) * 33 + tr], tile[(tc + 1) * 33 + tr]);
    o.u[1] = pkbf(tile[(tc + 2) * 33 + tr], tile[(tc + 3) * 33 + tr]);
    *(ushort4*)(out + (size_t)(c0 + tr) * R + r0 + tc) = o.us;
}

__global__ __launch_bounds__(256) void k1_mega(const float* __restrict__ x,
                                               const float* __restrict__ mask,
                                               const float* __restrict__ W1,
                                               const float* __restrict__ W2,
                                               const float* __restrict__ unpadded,
                                               float* __restrict__ part,
                                               float* __restrict__ cntp,
                                               ushort_t* __restrict__ W1t,
                                               ushort_t* __restrict__ W2t,
                                               float* __restrict__ scale,
                                               ushort_t* __restrict__ aggr,
                                               int* __restrict__ done) {
    __shared__ float smem[32 * 33];
    __shared__ int lastFlag;
    const int id = blockIdx.x;
    const int t  = threadIdx.x;

    if (id < 1024) {
        agg_core(x, mask, part, cntp, id, t);

        // --- last-block-per-b finalize (no spinning, one atomic per block) ---
        const int b = id >> 2;
        __threadfence();               // release: my partial stores -> coherency point
        __syncthreads();               // all threads' fences done before signal
        if (t == 0) {
            int old = atomicAdd(&done[b], 1);
            lastFlag = (old == 3);
        }
        __syncthreads();
        if (lastFlag) {
            __threadfence();           // acquire: discard stale cached partials
            const int d = 2 * t;
            float cnt = 0.f;
            #pragma unroll
            for (int c = 0; c < NCH; ++c) cnt += cntp[b * NCH + c];

            const size_t SS = (size_t)B_ * NCH * D_;
            float2 sum = {0.f, 0.f}, sq = {0.f, 0.f};
            float2 mx = {-INFINITY, -INFINITY}, mn = {INFINITY, INFINITY};
            #pragma unroll
            for (int c = 0; c < NCH; ++c) {
                const size_t pi = ((size_t)(b * NCH + c)) * D_ + d;
                float2 s  = *(const float2*)(part + 0 * SS + pi);
                float2 q  = *(const float2*)(part + 1 * SS + pi);
                float2 vx = *(const float2*)(part + 2 * SS + pi);
                float2 vn = *(const float2*)(part + 3 * SS + pi);
                sum.x += s.x; sum.y += s.y;
                sq.x  += q.x; sq.y  += q.y;
                mx.x = fmaxf(mx.x, vx.x); mx.y = fmaxf(mx.y, vx.y);
                mn.x = fminf(mn.x, vn.x); mn.y = fminf(mn.y, vn.y);
            }
            const float ic = 1.f / cnt;
            float2 mean = {sum.x * ic, sum.y * ic};
            float2 var  = {fmaxf(sq.x * ic - mean.x * mean.x, 0.f),
                           fmaxf(sq.y * ic - mean.y * mean.y, 0.f)};

            *(uint32_t*)(aggr + (size_t)(0 * B_ + b) * D_ + d) = pkbf(mean.x, mean.y);
            *(uint32_t*)(aggr + (size_t)(1 * B_ + b) * D_ + d) = pkbf(mx.x, mx.y);
            *(uint32_t*)(aggr + (size_t)(2 * B_ + b) * D_ + d) = pkbf(mn.x, mn.y);
            *(uint32_t*)(aggr + (size_t)(3 * B_ + b) * D_ + d) = pkbf(sqrtf(var.x), sqrtf(var.y));
        }
    } else if (id < 2048) {
        const int tid = id - 1024;
        conv_tile(W1, W1t, D_, H_, tid & 63, tid >> 6, smem);
    } else if (id < 3072) {
        const int tid = id - 2048;
        conv_tile(W2, W2t, H_, O_, tid & 15, tid >> 4, smem);
    } else {
        float4 u4 = *(const float4*)(unpadded + t * 4);
        smem[t] = u4.x + u4.y + u4.z + u4.w;
        __syncthreads();
        for (int s = 128; s > 0; s >>= 1) {
            if (t < s) smem[t] += smem[t + s];
            __syncthreads();
        }
        const float delta = smem[0] + 1.0f;
        float uu[4] = {u4.x, u4.y, u4.z, u4.w};
        #pragma unroll
        for (int j = 0; j < 4; ++j) {
            const int i = t * 4 + j;
            const float logu = logf(uu[j] + 1.0f);
            scale[i]          = 1.0f;
            scale[M4 + i]     = logu / delta;
            scale[2 * M4 + i] = delta / logu;
        }
    }
}

// ---------------------------------------------------------------------------
// K3: Z = aggr @ W1t^T, epilogue writes all 3 scaled h copies. (r11 verbatim)
// ---------------------------------------------------------------------------
__global__ __launch_bounds__(256) void gemm1_h(const ushort_t* __restrict__ A,
                                               const ushort_t* __restrict__ Bt,
                                               const float* __restrict__ scale,
                                               const float* __restrict__ b1,
                                               ushort_t* __restrict__ h) {
    __shared__ ushort_t As0[64 * 64], As1[64 * 64];
    __shared__ ushort_t Bs0[64 * 64], Bs1[64 * 64];

    const int t    = threadIdx.x;
    const int wave = t >> 6;
    const int lane = t & 63;
    const int wm   = wave >> 1, wn = wave & 1;
    const int row0 = blockIdx.y << 6;
    const int col0 = blockIdx.x << 6;

    const int lr  = lane >> 3;
    const int ksw = ((lane & 7) ^ lr) << 3;

    const int rl = lane & 15;
    const int hi = lane >> 4;

    const ushort_t* Ag0 = A  + (size_t)(row0 + wave * 8 + lr) * D_ + ksw;
    const ushort_t* Ag1 = A  + (size_t)(row0 + 32 + wave * 8 + lr) * D_ + ksw;
    const ushort_t* Bg0 = Bt + (size_t)(col0 + wave * 8 + lr) * D_ + ksw;
    const ushort_t* Bg1 = Bt + (size_t)(col0 + 32 + wave * 8 + lr) * D_ + ksw;
    const int ld0 = (wave * 8) * 64;
    const int ld1 = (32 + wave * 8) * 64;

    f32x4 acc[2][2] = {};

    ushort_t* Ac = As0; ushort_t* An = As1;
    ushort_t* Bc = Bs0; ushort_t* Bn = Bs1;

    load_lds16(Ag0, Ac + ld0); load_lds16(Ag1, Ac + ld1);
    load_lds16(Bg0, Bc + ld0); load_lds16(Bg1, Bc + ld1);
    __syncthreads();

    for (int tt = 0; tt < D_ / 64; ++tt) {
        const int k1 = (tt + 1) * 64;
        if (tt + 1 < D_ / 64) {
            load_lds16(Ag0 + k1, An + ld0); load_lds16(Ag1 + k1, An + ld1);
            load_lds16(Bg0 + k1, Bn + ld0); load_lds16(Bg1 + k1, Bn + ld1);
        }
        short8 av[2][2], bv[2][2];
        #pragma unroll
        for (int i = 0; i < 2; ++i) {
            const int ra = wm * 32 + i * 16 + rl;
            const int rb = wn * 32 + i * 16 + rl;
            #pragma unroll
            for (int k2 = 0; k2 < 2; ++k2) {
                av[i][k2] = *(const short8*)(Ac + ra * 64 + (((k2 * 4 + hi) ^ (ra & 7)) << 3));
                bv[i][k2] = *(const short8*)(Bc + rb * 64 + (((k2 * 4 + hi) ^ (rb & 7)) << 3));
            }
        }
        #pragma unroll
        for (int i = 0; i < 2; ++i)
            #pragma unroll
            for (int j = 0; j < 2; ++j)
                #pragma unroll
                for (int k2 = 0; k2 < 2; ++k2)
                    acc[i][j] = __builtin_amdgcn_mfma_f32_16x16x32_bf16(av[i][k2], bv[j][k2], acc[i][j], 0, 0, 0);
        __syncthreads();
        ushort_t* tp;
        tp = Ac; Ac = An; An = tp;
        tp = Bc; Bc = Bn; Bn = tp;
    }

    #pragma unroll
    for (int i = 0; i < 2; ++i) {
        #pragma unroll
        for (int v = 0; v < 4; ++v) {
            const int row = row0 + wm * 32 + i * 16 + hi * 4 + v;
            const float s1 = scale[M4 + row];
            const float s2 = scale[2 * M4 + row];
            #pragma unroll
            for (int j = 0; j < 2; ++j) {
                const int col = col0 + wn * 32 + j * 16 + rl;
                const float bb = b1[col];
                const float z  = acc[i][j][v];
                h[(size_t)row * H_ + col]            = f2bf(fmaxf(z + bb, 0.f));
                h[(size_t)(M4 + row) * H_ + col]     = f2bf(fmaxf(fmaf(s1, z, bb), 0.f));
                h[(size_t)(2 * M4 + row) * H_ + col] = f2bf(fmaxf(fmaf(s2, z, bb), 0.f));
            }
        }
    }
}

// ---------------------------------------------------------------------------
// K4: out = h @ W2t^T + b2. Pure GEMM, split-K in block. (r11 verbatim)
// ---------------------------------------------------------------------------
__global__ __launch_bounds__(512) void gemm2_pure(const ushort_t* __restrict__ h,
                                                  const ushort_t* __restrict__ W2t,
                                                  const float* __restrict__ b2,
                                                  float* __restrict__ out) {
    __shared__ ushort_t As[2][2][64 * 64];
    __shared__ ushort_t Bs[2][2][64 * 64];

    const int t    = threadIdx.x;
    const int wave = t >> 6;
    const int kg   = wave >> 2;
    const int w4   = wave & 3;
    const int lane = t & 63;
    const int wm   = w4 >> 1, wn = w4 & 1;

    const int id  = blockIdx.x;
    const int xcd = id & 7;
    const int idx = id >> 3;
    const int rb  = xcd * 6 + (idx % 6);
    const int cb  = idx / 6;
    const int row0 = rb << 6;
    const int col0 = cb << 6;

    const int lr  = lane >> 3;
    const int ksw = ((lane & 7) ^ lr) << 3;
    const int kbase = kg * (H_ / 2);

    const ushort_t* Ag0 = h   + (size_t)(row0 + w4 * 8 + lr) * H_ + kbase + ksw;
    const ushort_t* Ag1 = h   + (size_t)(row0 + 32 + w4 * 8 + lr) * H_ + kbase + ksw;
    const ushort_t* Bg0 = W2t + (size_t)(col0 + w4 * 8 + lr) * H_ + kbase + ksw;
    const ushort_t* Bg1 = W2t + (size_t)(col0 + 32 + w4 * 8 + lr) * H_ + kbase + ksw;
    const int ld0 = (w4 * 8) * 64;
    const int ld1 = (32 + w4 * 8) * 64;

    const int rl = lane & 15;
    const int hi = lane >> 4;

    f32x4 acc[2][2] = {};

    ushort_t* Ac = &As[kg][0][0]; ushort_t* An = &As[kg][1][0];
    ushort_t* Bc = &Bs[kg][0][0]; ushort_t* Bn = &Bs[kg][1][0];

    load_lds16(Ag0, Ac + ld0); load_lds16(Ag1, Ac + ld1);
    load_lds16(Bg0, Bc + ld0); load_lds16(Bg1, Bc + ld1);
    __syncthreads();

    for (int tt = 0; tt < 16; ++tt) {
        const int k1 = (tt + 1) * 64;
        if (tt + 1 < 16) {
            load_lds16(Ag0 + k1, An + ld0); load_lds16(Ag1 + k1, An + ld1);
            load_lds16(Bg0 + k1, Bn + ld0); load_lds16(Bg1 + k1, Bn + ld1);
        }
        short8 av[2][2], bv[2][2];
        #pragma unroll
        for (int i = 0; i < 2; ++i) {
            const int ra = wm * 32 + i * 16 + rl;
            const int rb2 = wn * 32 + i * 16 + rl;
            #pragma unroll
            for (int k2 = 0; k2 < 2; ++k2) {
                av[i][k2] = *(const short8*)(Ac + ra * 64 + (((k2 * 4 + hi) ^ (ra & 7)) << 3));
                bv[i][k2] = *(const short8*)(Bc + rb2 * 64 + (((k2 * 4 + hi) ^ (rb2 & 7)) << 3));
            }
        }
        #pragma unroll
        for (int i = 0; i < 2; ++i)
            #pragma unroll
            for (int j = 0; j < 2; ++j)
                #pragma unroll
                for (int k2 = 0; k2 < 2; ++k2)
                    acc[i][j] = __builtin_amdgcn_mfma_f32_16x16x32_bf16(av[i][k2], bv[j][k2], acc[i][j], 0, 0, 0);
        __syncthreads();
        ushort_t* tp;
        tp = Ac; Ac = An; An = tp;
        tp = Bc; Bc = Bn; Bn = tp;
    }

    float* red = (float*)&As[0][0][0];
    const int fidx = w4 * 1024 + lane * 16;
    if (kg == 1) {
        #pragma unroll
        for (int i = 0; i < 2; ++i)
            #pragma unroll
            for (int j = 0; j < 2; ++j)
                #pragma unroll
                for (int v = 0; v < 4; ++v)
                    red[fidx + i * 8 + j * 4 + v] = acc[i][j][v];
    }
    __syncthreads();
    if (kg == 0) {
        #pragma unroll
        for (int i = 0; i < 2; ++i)
            #pragma unroll
            for (int j = 0; j < 2; ++j) {
                const int col = col0 + wn * 32 + j * 16 + rl;
                const float bb = b2[col];
                #pragma unroll
                for (int v = 0; v < 4; ++v) {
                    const int row = row0 + wm * 32 + i * 16 + hi * 4 + v;
                    out[(size_t)row * O_ + col] =
                        acc[i][j][v] + red[fidx + i * 8 + j * 4 + v] + bb;
                }
            }
    }
}

// ---------------------------------------------------------------------------
extern "C" void kernel_launch(void* const* d_in, const int* in_sizes, int n_in,
                              void* d_out, int out_size, void* d_ws, size_t ws_size,
                              hipStream_t stream) {
    const float* x        = (const float*)d_in[0];
    const float* mask     = (const float*)d_in[1];
    const float* unpadded = (const float*)d_in[2];
    const float* W1       = (const float*)d_in[3];
    const float* b1       = (const float*)d_in[4];
    const float* W2       = (const float*)d_in[5];
    const float* b2       = (const float*)d_in[6];
    float* out = (float*)d_out;

    float* ws = (float*)d_ws;
    float* part  = ws;                        // 4,194,304 f32
    float* cntp  = ws + 4194304;              // 2048
    float* scale = ws + 4196352;              // 3072
    int*   done  = (int*)(ws + 4199424);      // 256 ints
    ushort_t* bfw  = (ushort_t*)(ws + 4200448);
    ushort_t* W1t  = bfw;                     // 2048*512
    ushort_t* W2t  = bfw + 1048576;           // 512*2048
    ushort_t* aggr = bfw + 2097152;           // 1024*512
    ushort_t* h    = bfw + 2621440;           // 3072*2048 bf16

    hipMemsetAsync(done, 0, 1024, stream);
    k1_mega<<<3073, 256, 0, stream>>>(x, mask, W1, W2, unpadded,
                                      part, cntp, W1t, W2t, scale, aggr, done);
    gemm1_h<<<dim3(H_ / 64, M4 / 64), 256, 0, stream>>>(aggr, W1t, scale, b1, h);
    gemm2_pure<<<384, 512, 0, stream>>>(h, W2t, b2, out);
}

// Round 15
// 126.413 us; speedup vs baseline: 2.9046x; 2.9046x over previous
//
#include <hip/hip_runtime.h>
#include <hip/hip_bf16.h>
#include <math.h>
#include <stdint.h>

#define B_  256
#define N_  1024
#define D_  512
#define H_  2048
#define O_  512
#define M4  (4 * B_)    // 1024 rows in aggr
#define M12 (12 * B_)   // 3072 rows in scale_concat
#define NCH 8           // partial chunks per b

typedef __attribute__((ext_vector_type(8))) short short8;
typedef __attribute__((ext_vector_type(4))) float f32x4;
typedef unsigned short ushort_t;

// packed f32x2 -> bf16x2 (RNE); compiler emits v_cvt_pk_bf16_f32
__device__ inline uint32_t pkbf(float a, float b) {
    union { __hip_bfloat162 h; uint32_t u; } cv;
    cv.h = __float22bfloat162_rn(float2{a, b});
    return cv.u;
}
// scalar f32 -> bf16 RNE
__device__ inline ushort_t f2bf(float f) {
    union { float f; uint32_t u; } v; v.f = f;
    uint32_t r = v.u + 0x7FFFu + ((v.u >> 16) & 1u);
    return (ushort_t)(r >> 16);
}

// async global->LDS 16B. LDS dest = wave-uniform base (HW adds lane*16).
__device__ inline void load_lds16(const void* g, void* l) {
    typedef const __attribute__((address_space(1))) uint32_t* gp_t;
    typedef __attribute__((address_space(3))) uint32_t* lp_t;
    __builtin_amdgcn_global_load_lds((gp_t)(uintptr_t)g, (lp_t)(uint32_t)(uintptr_t)l,
                                     16, 0, 0);
}

// ---------------------------------------------------------------------------
// agg core: per (b, n-chunk) partials. NT loads (stream-once), unroll 8.
// ---------------------------------------------------------------------------
__device__ __forceinline__ void agg_core(const float* __restrict__ x,
                                         const float* __restrict__ mask,
                                         float* __restrict__ part,
                                         float* __restrict__ cntp,
                                         int id, int t) {
    const int b    = id >> 2;
    const int c    = id & 3;
    const int half = t >> 7;
    const int d4   = (t & 127) << 2;
    const float* base = x + ((size_t)b * N_ + (size_t)c * 256) * D_ + d4;
    const float* mp   = mask + (size_t)b * N_ + (size_t)c * 256;

    f32x4 sum = {0.f,0.f,0.f,0.f}, sq = {0.f,0.f,0.f,0.f};
    f32x4 mx = {-INFINITY,-INFINITY,-INFINITY,-INFINITY};
    f32x4 mn = { INFINITY, INFINITY, INFINITY, INFINITY};
    float cnt = 0.f;

    #pragma unroll 8
    for (int n = half; n < 256; n += 2) {
        float m = mp[n];
        f32x4 v = __builtin_nontemporal_load((const f32x4*)(base + (size_t)n * D_));
        sum.x = fmaf(v.x, m, sum.x); sum.y = fmaf(v.y, m, sum.y);
        sum.z = fmaf(v.z, m, sum.z); sum.w = fmaf(v.w, m, sum.w);
        sq.x  = fmaf(v.x * v.x, m, sq.x); sq.y = fmaf(v.y * v.y, m, sq.y);
        sq.z  = fmaf(v.z * v.z, m, sq.z); sq.w = fmaf(v.w * v.w, m, sq.w);
        cnt  += m;
        bool um = m > 0.f;
        mx.x = um ? fmaxf(mx.x, v.x) : mx.x; mx.y = um ? fmaxf(mx.y, v.y) : mx.y;
        mx.z = um ? fmaxf(mx.z, v.z) : mx.z; mx.w = um ? fmaxf(mx.w, v.w) : mx.w;
        mn.x = um ? fminf(mn.x, v.x) : mn.x; mn.y = um ? fminf(mn.y, v.y) : mn.y;
        mn.z = um ? fminf(mn.z, v.z) : mn.z; mn.w = um ? fminf(mn.w, v.w) : mn.w;
    }

    const int ch = c * 2 + half;
    const size_t SS = (size_t)B_ * NCH * D_;
    const size_t pi = ((size_t)(b * NCH + ch)) * D_ + d4;
    *(f32x4*)(part + 0 * SS + pi) = sum;
    *(f32x4*)(part + 1 * SS + pi) = sq;
    *(f32x4*)(part + 2 * SS + pi) = mx;
    *(f32x4*)(part + 3 * SS + pi) = mn;
    if ((t & 127) == 0) cntp[b * NCH + ch] = cnt;
}

// ---------------------------------------------------------------------------
// K1 mega-kernel: agg partials [0,1024) | W1 conv [1024,2048) |
//                 W2 conv [2048,3072) | scales 3072
// ---------------------------------------------------------------------------
__device__ void conv_tile(const float* __restrict__ in, ushort_t* __restrict__ out,
                          int R, int C, int bx, int by, float* tile) {
    const int t  = threadIdx.x;
    const int r0 = by << 5;
    const int c0 = bx << 5;
    const int tr = t >> 3;
    const int tc = (t & 7) << 2;

    float4 v = *(const float4*)(in + (size_t)(r0 + tr) * C + c0 + tc);
    tile[tr * 33 + tc + 0] = v.x; tile[tr * 33 + tc + 1] = v.y;
    tile[tr * 33 + tc + 2] = v.z; tile[tr * 33 + tc + 3] = v.w;
    __syncthreads();

    union { uint32_t u[2]; ushort4 us; } o;
    o.u[0] = pkbf(tile[(tc + 0) * 33 + tr], tile[(tc + 1) * 33 + tr]);
    o.u[1] = pkbf(tile[(tc + 2) * 33 + tr], tile[(tc + 3) * 33 + tr]);
    *(ushort4*)(out + (size_t)(c0 + tr) * R + r0 + tc) = o.us;
}

__global__ __launch_bounds__(256) void k1_mega(const float* __restrict__ x,
                                               const float* __restrict__ mask,
                                               const float* __restrict__ W1,
                                               const float* __restrict__ W2,
                                               const float* __restrict__ unpadded,
                                               float* __restrict__ part,
                                               float* __restrict__ cntp,
                                               ushort_t* __restrict__ W1t,
                                               ushort_t* __restrict__ W2t,
                                               float* __restrict__ scale) {
    __shared__ float smem[32 * 33];
    const int id = blockIdx.x;
    const int t  = threadIdx.x;

    if (id < 1024) {
        agg_core(x, mask, part, cntp, id, t);
    } else if (id < 2048) {
        const int tid = id - 1024;
        conv_tile(W1, W1t, D_, H_, tid & 63, tid >> 6, smem);
    } else if (id < 3072) {
        const int tid = id - 2048;
        conv_tile(W2, W2t, H_, O_, tid & 15, tid >> 4, smem);
    } else {
        float4 u4 = *(const float4*)(unpadded + t * 4);
        smem[t] = u4.x + u4.y + u4.z + u4.w;
        __syncthreads();
        for (int s = 128; s > 0; s >>= 1) {
            if (t < s) smem[t] += smem[t + s];
            __syncthreads();
        }
        const float delta = smem[0] + 1.0f;
        float uu[4] = {u4.x, u4.y, u4.z, u4.w};
        #pragma unroll
        for (int j = 0; j < 4; ++j) {
            const int i = t * 4 + j;
            const float logu = logf(uu[j] + 1.0f);
            scale[i]          = 1.0f;
            scale[M4 + i]     = logu / delta;
            scale[2 * M4 + i] = delta / logu;
        }
    }
}

// ---------------------------------------------------------------------------
// K2: combine NCH chunks -> bf16 aggr [1024 x 512]. 256 thr, float2/thread.
// ---------------------------------------------------------------------------
__global__ __launch_bounds__(256) void agg_final(const float* __restrict__ part,
                                                 const float* __restrict__ cntp,
                                                 ushort_t* __restrict__ aggr) {
    const int b = blockIdx.x;
    const int t = threadIdx.x;
    const int d = 2 * t;

    float cnt = 0.f;
    #pragma unroll
    for (int c = 0; c < NCH; ++c) cnt += cntp[b * NCH + c];

    const size_t SS = (size_t)B_ * NCH * D_;
    float2 sum = {0.f, 0.f}, sq = {0.f, 0.f};
    float2 mx = {-INFINITY, -INFINITY}, mn = {INFINITY, INFINITY};
    #pragma unroll
    for (int c = 0; c < NCH; ++c) {
        const size_t pi = ((size_t)(b * NCH + c)) * D_ + d;
        float2 s  = *(const float2*)(part + 0 * SS + pi);
        float2 q  = *(const float2*)(part + 1 * SS + pi);
        float2 vx = *(const float2*)(part + 2 * SS + pi);
        float2 vn = *(const float2*)(part + 3 * SS + pi);
        sum.x += s.x; sum.y += s.y;
        sq.x  += q.x; sq.y  += q.y;
        mx.x = fmaxf(mx.x, vx.x); mx.y = fmaxf(mx.y, vx.y);
        mn.x = fminf(mn.x, vn.x); mn.y = fminf(mn.y, vn.y);
    }
    const float ic = 1.f / cnt;
    float2 mean = {sum.x * ic, sum.y * ic};
    float2 var  = {fmaxf(sq.x * ic - mean.x * mean.x, 0.f),
                   fmaxf(sq.y * ic - mean.y * mean.y, 0.f)};

    *(uint32_t*)(aggr + (size_t)(0 * B_ + b) * D_ + d) = pkbf(mean.x, mean.y);
    *(uint32_t*)(aggr + (size_t)(1 * B_ + b) * D_ + d) = pkbf(mx.x, mx.y);
    *(uint32_t*)(aggr + (size_t)(2 * B_ + b) * D_ + d) = pkbf(mn.x, mn.y);
    *(uint32_t*)(aggr + (size_t)(3 * B_ + b) * D_ + d) = pkbf(sqrtf(var.x), sqrtf(var.y));
}

// ---------------------------------------------------------------------------
// K3: Z = aggr @ W1t^T  [1024 x 2048], K=512. Tile 64x64, BK=64, 4 waves.
// Epilogue materializes all 3 scaled copies of h = bf16(relu(s*Z + b1)).
// ---------------------------------------------------------------------------
__global__ __launch_bounds__(256) void gemm1_h(const ushort_t* __restrict__ A,
                                               const ushort_t* __restrict__ Bt,
                                               const float* __restrict__ scale,
                                               const float* __restrict__ b1,
                                               ushort_t* __restrict__ h) {
    __shared__ ushort_t As0[64 * 64], As1[64 * 64];
    __shared__ ushort_t Bs0[64 * 64], Bs1[64 * 64];

    const int t    = threadIdx.x;
    const int wave = t >> 6;
    const int lane = t & 63;
    const int wm   = wave >> 1, wn = wave & 1;
    const int row0 = blockIdx.y << 6;
    const int col0 = blockIdx.x << 6;

    const int lr  = lane >> 3;
    const int ksw = ((lane & 7) ^ lr) << 3;

    const int rl = lane & 15;
    const int hi = lane >> 4;

    const ushort_t* Ag0 = A  + (size_t)(row0 + wave * 8 + lr) * D_ + ksw;
    const ushort_t* Ag1 = A  + (size_t)(row0 + 32 + wave * 8 + lr) * D_ + ksw;
    const ushort_t* Bg0 = Bt + (size_t)(col0 + wave * 8 + lr) * D_ + ksw;
    const ushort_t* Bg1 = Bt + (size_t)(col0 + 32 + wave * 8 + lr) * D_ + ksw;
    const int ld0 = (wave * 8) * 64;
    const int ld1 = (32 + wave * 8) * 64;

    f32x4 acc[2][2] = {};

    ushort_t* Ac = As0; ushort_t* An = As1;
    ushort_t* Bc = Bs0; ushort_t* Bn = Bs1;

    load_lds16(Ag0, Ac + ld0); load_lds16(Ag1, Ac + ld1);
    load_lds16(Bg0, Bc + ld0); load_lds16(Bg1, Bc + ld1);
    __syncthreads();

    for (int tt = 0; tt < D_ / 64; ++tt) {
        const int k1 = (tt + 1) * 64;
        if (tt + 1 < D_ / 64) {
            load_lds16(Ag0 + k1, An + ld0); load_lds16(Ag1 + k1, An + ld1);
            load_lds16(Bg0 + k1, Bn + ld0); load_lds16(Bg1 + k1, Bn + ld1);
        }
        short8 av[2][2], bv[2][2];
        #pragma unroll
        for (int i = 0; i < 2; ++i) {
            const int ra = wm * 32 + i * 16 + rl;
            const int rb = wn * 32 + i * 16 + rl;
            #pragma unroll
            for (int k2 = 0; k2 < 2; ++k2) {
                av[i][k2] = *(const short8*)(Ac + ra * 64 + (((k2 * 4 + hi) ^ (ra & 7)) << 3));
                bv[i][k2] = *(const short8*)(Bc + rb * 64 + (((k2 * 4 + hi) ^ (rb & 7)) << 3));
            }
        }
        #pragma unroll
        for (int i = 0; i < 2; ++i)
            #pragma unroll
            for (int j = 0; j < 2; ++j)
                #pragma unroll
                for (int k2 = 0; k2 < 2; ++k2)
                    acc[i][j] = __builtin_amdgcn_mfma_f32_16x16x32_bf16(av[i][k2], bv[j][k2], acc[i][j], 0, 0, 0);
        __syncthreads();
        ushort_t* tp;
        tp = Ac; Ac = An; An = tp;
        tp = Bc; Bc = Bn; Bn = tp;
    }

    // epilogue: h rows {row, M4+row, 2*M4+row}; s0 = 1 exactly.
    #pragma unroll
    for (int i = 0; i < 2; ++i) {
        #pragma unroll
        for (int v = 0; v < 4; ++v) {
            const int row = row0 + wm * 32 + i * 16 + hi * 4 + v;
            const float s1 = scale[M4 + row];
            const float s2 = scale[2 * M4 + row];
            #pragma unroll
            for (int j = 0; j < 2; ++j) {
                const int col = col0 + wn * 32 + j * 16 + rl;
                const float bb = b1[col];
                const float z  = acc[i][j][v];
                h[(size_t)row * H_ + col]            = f2bf(fmaxf(z + bb, 0.f));
                h[(size_t)(M4 + row) * H_ + col]     = f2bf(fmaxf(fmaf(s1, z, bb), 0.f));
                h[(size_t)(2 * M4 + row) * H_ + col] = f2bf(fmaxf(fmaf(s2, z, bb), 0.f));
            }
        }
    }
}

// ---------------------------------------------------------------------------
// K4: out = h @ W2t^T + b2  [3072 x 512], K=2048. Pure GEMM, tile 64x64.
// 512 threads = 8 waves, in-block split-K (2 groups), 2-phase dbuf,
// 384 blocks with XCD-aware mapping.
// ---------------------------------------------------------------------------
__global__ __launch_bounds__(512) void gemm2_pure(const ushort_t* __restrict__ h,
                                                  const ushort_t* __restrict__ W2t,
                                                  const float* __restrict__ b2,
                                                  float* __restrict__ out) {
    __shared__ ushort_t As[2][2][64 * 64];   // [kg][buf] 32 KB
    __shared__ ushort_t Bs[2][2][64 * 64];   // 32 KB

    const int t    = threadIdx.x;
    const int wave = t >> 6;       // 0..7
    const int kg   = wave >> 2;    // K-group 0/1
    const int w4   = wave & 3;
    const int lane = t & 63;
    const int wm   = w4 >> 1, wn = w4 & 1;

    const int id  = blockIdx.x;    // 0..383
    const int xcd = id & 7;
    const int idx = id >> 3;
    const int rb  = xcd * 6 + (idx % 6);
    const int cb  = idx / 6;
    const int row0 = rb << 6;
    const int col0 = cb << 6;

    const int lr  = lane >> 3;
    const int ksw = ((lane & 7) ^ lr) << 3;
    const int kbase = kg * (H_ / 2);

    const ushort_t* Ag0 = h   + (size_t)(row0 + w4 * 8 + lr) * H_ + kbase + ksw;
    const ushort_t* Ag1 = h   + (size_t)(row0 + 32 + w4 * 8 + lr) * H_ + kbase + ksw;
    const ushort_t* Bg0 = W2t + (size_t)(col0 + w4 * 8 + lr) * H_ + kbase + ksw;
    const ushort_t* Bg1 = W2t + (size_t)(col0 + 32 + w4 * 8 + lr) * H_ + kbase + ksw;
    const int ld0 = (w4 * 8) * 64;
    const int ld1 = (32 + w4 * 8) * 64;

    const int rl = lane & 15;
    const int hi = lane >> 4;

    f32x4 acc[2][2] = {};

    ushort_t* Ac = &As[kg][0][0]; ushort_t* An = &As[kg][1][0];
    ushort_t* Bc = &Bs[kg][0][0]; ushort_t* Bn = &Bs[kg][1][0];

    load_lds16(Ag0, Ac + ld0); load_lds16(Ag1, Ac + ld1);
    load_lds16(Bg0, Bc + ld0); load_lds16(Bg1, Bc + ld1);
    __syncthreads();

    for (int tt = 0; tt < 16; ++tt) {
        const int k1 = (tt + 1) * 64;
        if (tt + 1 < 16) {
            load_lds16(Ag0 + k1, An + ld0); load_lds16(Ag1 + k1, An + ld1);
            load_lds16(Bg0 + k1, Bn + ld0); load_lds16(Bg1 + k1, Bn + ld1);
        }
        short8 av[2][2], bv[2][2];
        #pragma unroll
        for (int i = 0; i < 2; ++i) {
            const int ra = wm * 32 + i * 16 + rl;
            const int rb2 = wn * 32 + i * 16 + rl;
            #pragma unroll
            for (int k2 = 0; k2 < 2; ++k2) {
                av[i][k2] = *(const short8*)(Ac + ra * 64 + (((k2 * 4 + hi) ^ (ra & 7)) << 3));
                bv[i][k2] = *(const short8*)(Bc + rb2 * 64 + (((k2 * 4 + hi) ^ (rb2 & 7)) << 3));
            }
        }
        #pragma unroll
        for (int i = 0; i < 2; ++i)
            #pragma unroll
            for (int j = 0; j < 2; ++j)
                #pragma unroll
                for (int k2 = 0; k2 < 2; ++k2)
                    acc[i][j] = __builtin_amdgcn_mfma_f32_16x16x32_bf16(av[i][k2], bv[j][k2], acc[i][j], 0, 0, 0);
        __syncthreads();
        ushort_t* tp;
        tp = Ac; Ac = An; An = tp;
        tp = Bc; Bc = Bn; Bn = tp;
    }

    // combine the two K-halves via LDS scratch (reuse As region, 16 KB).
    float* red = (float*)&As[0][0][0];
    const int fidx = w4 * 1024 + lane * 16;
    if (kg == 1) {
        #pragma unroll
        for (int i = 0; i < 2; ++i)
            #pragma unroll
            for (int j = 0; j < 2; ++j)
                #pragma unroll
                for (int v = 0; v < 4; ++v)
                    red[fidx + i * 8 + j * 4 + v] = acc[i][j][v];
    }
    __syncthreads();
    if (kg == 0) {
        #pragma unroll
        for (int i = 0; i < 2; ++i)
            #pragma unroll
            for (int j = 0; j < 2; ++j) {
                const int col = col0 + wn * 32 + j * 16 + rl;
                const float bb = b2[col];
                #pragma unroll
                for (int v = 0; v < 4; ++v) {
                    const int row = row0 + wm * 32 + i * 16 + hi * 4 + v;
                    out[(size_t)row * O_ + col] =
                        acc[i][j][v] + red[fidx + i * 8 + j * 4 + v] + bb;
                }
            }
    }
}

// ---------------------------------------------------------------------------
extern "C" void kernel_launch(void* const* d_in, const int* in_sizes, int n_in,
                              void* d_out, int out_size, void* d_ws, size_t ws_size,
                              hipStream_t stream) {
    const float* x        = (const float*)d_in[0];
    const float* mask     = (const float*)d_in[1];
    const float* unpadded = (const float*)d_in[2];
    const float* W1       = (const float*)d_in[3];
    const float* b1       = (const float*)d_in[4];
    const float* W2       = (const float*)d_in[5];
    const float* b2       = (const float*)d_in[6];
    float* out = (float*)d_out;

    float* ws = (float*)d_ws;
    float* part  = ws;                        // 4,194,304 f32
    float* cntp  = ws + 4194304;              // 2048
    float* scale = ws + 4196352;              // 3072
    ushort_t* bfw  = (ushort_t*)(ws + 4200448);
    ushort_t* W1t  = bfw;                     // 2048*512
    ushort_t* W2t  = bfw + 1048576;           // 512*2048
    ushort_t* aggr = bfw + 2097152;           // 1024*512
    ushort_t* h    = bfw + 2621440;           // 3072*2048 bf16 (12 MB)

    k1_mega<<<3073, 256, 0, stream>>>(x, mask, W1, W2, unpadded,
                                      part, cntp, W1t, W2t, scale);
    agg_final<<<B_, 256, 0, stream>>>(part, cntp, aggr);
    gemm1_h<<<dim3(H_ / 64, M4 / 64), 256, 0, stream>>>(aggr, W1t, scale, b1, h);
    gemm2_pure<<<384, 512, 0, stream>>>(h, W2t, b2, out);
}

// Round 16
// 113.628 us; speedup vs baseline: 3.2314x; 1.1125x over previous
//
#include <hip/hip_runtime.h>
#include <hip/hip_bf16.h>
#include <math.h>
#include <stdint.h>

#define B_  256
#define N_  1024
#define D_  512
#define H_  2048
#define O_  512
#define M4  (4 * B_)    // 1024 rows in aggr
#define M12 (12 * B_)   // 3072 rows in scale_concat

typedef __attribute__((ext_vector_type(8))) short short8;
typedef __attribute__((ext_vector_type(4))) float f32x4;
typedef unsigned short ushort_t;

// packed f32x2 -> bf16x2 (RNE); compiler emits v_cvt_pk_bf16_f32
__device__ inline uint32_t pkbf(float a, float b) {
    union { __hip_bfloat162 h; uint32_t u; } cv;
    cv.h = __float22bfloat162_rn(float2{a, b});
    return cv.u;
}
// scalar f32 -> bf16 RNE
__device__ inline ushort_t f2bf(float f) {
    union { float f; uint32_t u; } v; v.f = f;
    uint32_t r = v.u + 0x7FFFu + ((v.u >> 16) & 1u);
    return (ushort_t)(r >> 16);
}

// async global->LDS 16B. LDS dest = wave-uniform base (HW adds lane*16).
__device__ inline void load_lds16(const void* g, void* l) {
    typedef const __attribute__((address_space(1))) uint32_t* gp_t;
    typedef __attribute__((address_space(3))) uint32_t* lp_t;
    __builtin_amdgcn_global_load_lds((gp_t)(uintptr_t)g, (lp_t)(uint32_t)(uintptr_t)l,
                                     16, 0, 0);
}

// ---------------------------------------------------------------------------
// K1 mega-kernel:
//   [0,512)       full-N aggregation: block = (b, d-half); 4 waves split rows
//                 n%4; LDS combine; finalize + write bf16 aggr directly.
//   [512,1536)    W1 [512x2048] -> bf16 W1t [2048x512]
//   [1536,2560)   W2 [2048x512] -> bf16 W2t [512x2048]
//   2560          delta + per-row scales
// ---------------------------------------------------------------------------
__device__ void conv_tile(const float* __restrict__ in, ushort_t* __restrict__ out,
                          int R, int C, int bx, int by, float* tile) {
    const int t  = threadIdx.x;
    const int r0 = by << 5;
    const int c0 = bx << 5;
    const int tr = t >> 3;
    const int tc = (t & 7) << 2;

    float4 v = *(const float4*)(in + (size_t)(r0 + tr) * C + c0 + tc);
    tile[tr * 33 + tc + 0] = v.x; tile[tr * 33 + tc + 1] = v.y;
    tile[tr * 33 + tc + 2] = v.z; tile[tr * 33 + tc + 3] = v.w;
    __syncthreads();

    union { uint32_t u[2]; ushort4 us; } o;
    o.u[0] = pkbf(tile[(tc + 0) * 33 + tr], tile[(tc + 1) * 33 + tr]);
    o.u[1] = pkbf(tile[(tc + 2) * 33 + tr], tile[(tc + 3) * 33 + tr]);
    *(ushort4*)(out + (size_t)(c0 + tr) * R + r0 + tc) = o.us;
}

__global__ __launch_bounds__(256) void k1_mega(const float* __restrict__ x,
                                               const float* __restrict__ mask,
                                               const float* __restrict__ W1,
                                               const float* __restrict__ W2,
                                               const float* __restrict__ unpadded,
                                               ushort_t* __restrict__ W1t,
                                               ushort_t* __restrict__ W2t,
                                               float* __restrict__ scale,
                                               ushort_t* __restrict__ aggr) {
    __shared__ char smem_raw[16448];
    const int id = blockIdx.x;
    const int t  = threadIdx.x;

    if (id < 512) {
        // ---- full-N aggregation for (b, half) ----
        const int b    = id >> 1;
        const int half = id & 1;
        const int wv   = t >> 6;          // 0..3: rows n % 4
        const int lane = t & 63;
        const int d    = half * 256 + lane * 4;
        const float* base = x + (size_t)b * N_ * D_ + d;
        const float* mp   = mask + (size_t)b * N_;

        f32x4 sum = {0.f,0.f,0.f,0.f}, sq = {0.f,0.f,0.f,0.f};
        f32x4 mx = {-INFINITY,-INFINITY,-INFINITY,-INFINITY};
        f32x4 mn = { INFINITY, INFINITY, INFINITY, INFINITY};
        float cnt = 0.f;

        #pragma unroll 8
        for (int n = wv; n < N_; n += 4) {
            float m = mp[n];
            f32x4 v = __builtin_nontemporal_load((const f32x4*)(base + (size_t)n * D_));
            sum.x = fmaf(v.x, m, sum.x); sum.y = fmaf(v.y, m, sum.y);
            sum.z = fmaf(v.z, m, sum.z); sum.w = fmaf(v.w, m, sum.w);
            sq.x  = fmaf(v.x * v.x, m, sq.x); sq.y = fmaf(v.y * v.y, m, sq.y);
            sq.z  = fmaf(v.z * v.z, m, sq.z); sq.w = fmaf(v.w * v.w, m, sq.w);
            cnt  += m;
            bool um = m > 0.f;
            mx.x = um ? fmaxf(mx.x, v.x) : mx.x; mx.y = um ? fmaxf(mx.y, v.y) : mx.y;
            mx.z = um ? fmaxf(mx.z, v.z) : mx.z; mx.w = um ? fmaxf(mx.w, v.w) : mx.w;
            mn.x = um ? fminf(mn.x, v.x) : mn.x; mn.y = um ? fminf(mn.y, v.y) : mn.y;
            mn.z = um ? fminf(mn.z, v.z) : mn.z; mn.w = um ? fminf(mn.w, v.w) : mn.w;
        }

        f32x4* Lsum = (f32x4*)(smem_raw);
        f32x4* Lsq  = (f32x4*)(smem_raw + 4096);
        f32x4* Lmx  = (f32x4*)(smem_raw + 8192);
        f32x4* Lmn  = (f32x4*)(smem_raw + 12288);
        float* Lc   = (float*)(smem_raw + 16384);
        Lsum[wv * 64 + lane] = sum;
        Lsq [wv * 64 + lane] = sq;
        Lmx [wv * 64 + lane] = mx;
        Lmn [wv * 64 + lane] = mn;
        if (lane == 0) Lc[wv] = cnt;
        __syncthreads();

        if (wv == 0) {
            #pragma unroll
            for (int w = 1; w < 4; ++w) {
                f32x4 s = Lsum[w * 64 + lane];
                f32x4 q = Lsq [w * 64 + lane];
                f32x4 X = Lmx [w * 64 + lane];
                f32x4 M = Lmn [w * 64 + lane];
                sum.x += s.x; sum.y += s.y; sum.z += s.z; sum.w += s.w;
                sq.x  += q.x; sq.y  += q.y; sq.z  += q.z; sq.w  += q.w;
                mx.x = fmaxf(mx.x, X.x); mx.y = fmaxf(mx.y, X.y);
                mx.z = fmaxf(mx.z, X.z); mx.w = fmaxf(mx.w, X.w);
                mn.x = fminf(mn.x, M.x); mn.y = fminf(mn.y, M.y);
                mn.z = fminf(mn.z, M.z); mn.w = fminf(mn.w, M.w);
            }
            const float c  = Lc[0] + Lc[1] + Lc[2] + Lc[3];
            const float ic = 1.f / c;
            f32x4 mean = {sum.x * ic, sum.y * ic, sum.z * ic, sum.w * ic};
            f32x4 var  = {fmaxf(sq.x * ic - mean.x * mean.x, 0.f),
                          fmaxf(sq.y * ic - mean.y * mean.y, 0.f),
                          fmaxf(sq.z * ic - mean.z * mean.z, 0.f),
                          fmaxf(sq.w * ic - mean.w * mean.w, 0.f)};

            union { uint32_t u[2]; ushort4 us; } o;
            o.u[0] = pkbf(mean.x, mean.y); o.u[1] = pkbf(mean.z, mean.w);
            *(ushort4*)(aggr + (size_t)(0 * B_ + b) * D_ + d) = o.us;
            o.u[0] = pkbf(mx.x, mx.y); o.u[1] = pkbf(mx.z, mx.w);
            *(ushort4*)(aggr + (size_t)(1 * B_ + b) * D_ + d) = o.us;
            o.u[0] = pkbf(mn.x, mn.y); o.u[1] = pkbf(mn.z, mn.w);
            *(ushort4*)(aggr + (size_t)(2 * B_ + b) * D_ + d) = o.us;
            o.u[0] = pkbf(sqrtf(var.x), sqrtf(var.y));
            o.u[1] = pkbf(sqrtf(var.z), sqrtf(var.w));
            *(ushort4*)(aggr + (size_t)(3 * B_ + b) * D_ + d) = o.us;
        }
    } else if (id < 1536) {
        const int tid = id - 512;
        conv_tile(W1, W1t, D_, H_, tid & 63, tid >> 6, (float*)smem_raw);
    } else if (id < 2560) {
        const int tid = id - 1536;
        conv_tile(W2, W2t, H_, O_, tid & 15, tid >> 4, (float*)smem_raw);
    } else {
        float* smem = (float*)smem_raw;
        float4 u4 = *(const float4*)(unpadded + t * 4);
        smem[t] = u4.x + u4.y + u4.z + u4.w;
        __syncthreads();
        for (int s = 128; s > 0; s >>= 1) {
            if (t < s) smem[t] += smem[t + s];
            __syncthreads();
        }
        const float delta = smem[0] + 1.0f;
        float uu[4] = {u4.x, u4.y, u4.z, u4.w};
        #pragma unroll
        for (int j = 0; j < 4; ++j) {
            const int i = t * 4 + j;
            const float logu = logf(uu[j] + 1.0f);
            scale[i]          = 1.0f;
            scale[M4 + i]     = logu / delta;
            scale[2 * M4 + i] = delta / logu;
        }
    }
}

// ---------------------------------------------------------------------------
// K3: Z = aggr @ W1t^T  [1024 x 2048], K=512. Tile 64x64, BK=64, 4 waves.
// Epilogue materializes all 3 scaled copies of h = bf16(relu(s*Z + b1)).
// ---------------------------------------------------------------------------
__global__ __launch_bounds__(256) void gemm1_h(const ushort_t* __restrict__ A,
                                               const ushort_t* __restrict__ Bt,
                                               const float* __restrict__ scale,
                                               const float* __restrict__ b1,
                                               ushort_t* __restrict__ h) {
    __shared__ ushort_t As0[64 * 64], As1[64 * 64];
    __shared__ ushort_t Bs0[64 * 64], Bs1[64 * 64];

    const int t    = threadIdx.x;
    const int wave = t >> 6;
    const int lane = t & 63;
    const int wm   = wave >> 1, wn = wave & 1;
    const int row0 = blockIdx.y << 6;
    const int col0 = blockIdx.x << 6;

    const int lr  = lane >> 3;
    const int ksw = ((lane & 7) ^ lr) << 3;

    const int rl = lane & 15;
    const int hi = lane >> 4;

    const ushort_t* Ag0 = A  + (size_t)(row0 + wave * 8 + lr) * D_ + ksw;
    const ushort_t* Ag1 = A  + (size_t)(row0 + 32 + wave * 8 + lr) * D_ + ksw;
    const ushort_t* Bg0 = Bt + (size_t)(col0 + wave * 8 + lr) * D_ + ksw;
    const ushort_t* Bg1 = Bt + (size_t)(col0 + 32 + wave * 8 + lr) * D_ + ksw;
    const int ld0 = (wave * 8) * 64;
    const int ld1 = (32 + wave * 8) * 64;

    f32x4 acc[2][2] = {};

    ushort_t* Ac = As0; ushort_t* An = As1;
    ushort_t* Bc = Bs0; ushort_t* Bn = Bs1;

    load_lds16(Ag0, Ac + ld0); load_lds16(Ag1, Ac + ld1);
    load_lds16(Bg0, Bc + ld0); load_lds16(Bg1, Bc + ld1);
    __syncthreads();

    for (int tt = 0; tt < D_ / 64; ++tt) {
        const int k1 = (tt + 1) * 64;
        if (tt + 1 < D_ / 64) {
            load_lds16(Ag0 + k1, An + ld0); load_lds16(Ag1 + k1, An + ld1);
            load_lds16(Bg0 + k1, Bn + ld0); load_lds16(Bg1 + k1, Bn + ld1);
        }
        short8 av[2][2], bv[2][2];
        #pragma unroll
        for (int i = 0; i < 2; ++i) {
            const int ra = wm * 32 + i * 16 + rl;
            const int rb = wn * 32 + i * 16 + rl;
            #pragma unroll
            for (int k2 = 0; k2 < 2; ++k2) {
                av[i][k2] = *(const short8*)(Ac + ra * 64 + (((k2 * 4 + hi) ^ (ra & 7)) << 3));
                bv[i][k2] = *(const short8*)(Bc + rb * 64 + (((k2 * 4 + hi) ^ (rb & 7)) << 3));
            }
        }
        #pragma unroll
        for (int i = 0; i < 2; ++i)
            #pragma unroll
            for (int j = 0; j < 2; ++j)
                #pragma unroll
                for (int k2 = 0; k2 < 2; ++k2)
                    acc[i][j] = __builtin_amdgcn_mfma_f32_16x16x32_bf16(av[i][k2], bv[j][k2], acc[i][j], 0, 0, 0);
        __syncthreads();
        ushort_t* tp;
        tp = Ac; Ac = An; An = tp;
        tp = Bc; Bc = Bn; Bn = tp;
    }

    // epilogue: h rows {row, M4+row, 2*M4+row}; s0 = 1 exactly.
    #pragma unroll
    for (int i = 0; i < 2; ++i) {
        #pragma unroll
        for (int v = 0; v < 4; ++v) {
            const int row = row0 + wm * 32 + i * 16 + hi * 4 + v;
            const float s1 = scale[M4 + row];
            const float s2 = scale[2 * M4 + row];
            #pragma unroll
            for (int j = 0; j < 2; ++j) {
                const int col = col0 + wn * 32 + j * 16 + rl;
                const float bb = b1[col];
                const float z  = acc[i][j][v];
                h[(size_t)row * H_ + col]            = f2bf(fmaxf(z + bb, 0.f));
                h[(size_t)(M4 + row) * H_ + col]     = f2bf(fmaxf(fmaf(s1, z, bb), 0.f));
                h[(size_t)(2 * M4 + row) * H_ + col] = f2bf(fmaxf(fmaf(s2, z, bb), 0.f));
            }
        }
    }
}

// ---------------------------------------------------------------------------
// K4: out = h @ W2t^T + b2  [3072 x 512], K=2048. Pure GEMM, tile 64x64.
// 512 threads = 8 waves, in-block split-K (2 groups), 2-phase dbuf,
// 384 blocks with XCD-aware mapping.
// ---------------------------------------------------------------------------
__global__ __launch_bounds__(512) void gemm2_pure(const ushort_t* __restrict__ h,
                                                  const ushort_t* __restrict__ W2t,
                                                  const float* __restrict__ b2,
                                                  float* __restrict__ out) {
    __shared__ ushort_t As[2][2][64 * 64];   // [kg][buf] 32 KB
    __shared__ ushort_t Bs[2][2][64 * 64];   // 32 KB

    const int t    = threadIdx.x;
    const int wave = t >> 6;       // 0..7
    const int kg   = wave >> 2;    // K-group 0/1
    const int w4   = wave & 3;
    const int lane = t & 63;
    const int wm   = w4 >> 1, wn = w4 & 1;

    const int id  = blockIdx.x;    // 0..383
    const int xcd = id & 7;
    const int idx = id >> 3;
    const int rb  = xcd * 6 + (idx % 6);
    const int cb  = idx / 6;
    const int row0 = rb << 6;
    const int col0 = cb << 6;

    const int lr  = lane >> 3;
    const int ksw = ((lane & 7) ^ lr) << 3;
    const int kbase = kg * (H_ / 2);

    const ushort_t* Ag0 = h   + (size_t)(row0 + w4 * 8 + lr) * H_ + kbase + ksw;
    const ushort_t* Ag1 = h   + (size_t)(row0 + 32 + w4 * 8 + lr) * H_ + kbase + ksw;
    const ushort_t* Bg0 = W2t + (size_t)(col0 + w4 * 8 + lr) * H_ + kbase + ksw;
    const ushort_t* Bg1 = W2t + (size_t)(col0 + 32 + w4 * 8 + lr) * H_ + kbase + ksw;
    const int ld0 = (w4 * 8) * 64;
    const int ld1 = (32 + w4 * 8) * 64;

    const int rl = lane & 15;
    const int hi = lane >> 4;

    f32x4 acc[2][2] = {};

    ushort_t* Ac = &As[kg][0][0]; ushort_t* An = &As[kg][1][0];
    ushort_t* Bc = &Bs[kg][0][0]; ushort_t* Bn = &Bs[kg][1][0];

    load_lds16(Ag0, Ac + ld0); load_lds16(Ag1, Ac + ld1);
    load_lds16(Bg0, Bc + ld0); load_lds16(Bg1, Bc + ld1);
    __syncthreads();

    for (int tt = 0; tt < 16; ++tt) {
        const int k1 = (tt + 1) * 64;
        if (tt + 1 < 16) {
            load_lds16(Ag0 + k1, An + ld0); load_lds16(Ag1 + k1, An + ld1);
            load_lds16(Bg0 + k1, Bn + ld0); load_lds16(Bg1 + k1, Bn + ld1);
        }
        short8 av[2][2], bv[2][2];
        #pragma unroll
        for (int i = 0; i < 2; ++i) {
            const int ra = wm * 32 + i * 16 + rl;
            const int rb2 = wn * 32 + i * 16 + rl;
            #pragma unroll
            for (int k2 = 0; k2 < 2; ++k2) {
                av[i][k2] = *(const short8*)(Ac + ra * 64 + (((k2 * 4 + hi) ^ (ra & 7)) << 3));
                bv[i][k2] = *(const short8*)(Bc + rb2 * 64 + (((k2 * 4 + hi) ^ (rb2 & 7)) << 3));
            }
        }
        #pragma unroll
        for (int i = 0; i < 2; ++i)
            #pragma unroll
            for (int j = 0; j < 2; ++j)
                #pragma unroll
                for (int k2 = 0; k2 < 2; ++k2)
                    acc[i][j] = __builtin_amdgcn_mfma_f32_16x16x32_bf16(av[i][k2], bv[j][k2], acc[i][j], 0, 0, 0);
        __syncthreads();
        ushort_t* tp;
        tp = Ac; Ac = An; An = tp;
        tp = Bc; Bc = Bn; Bn = tp;
    }

    // combine the two K-halves via LDS scratch (reuse As region, 16 KB).
    float* red = (float*)&As[0][0][0];
    const int fidx = w4 * 1024 + lane * 16;
    if (kg == 1) {
        #pragma unroll
        for (int i = 0; i < 2; ++i)
            #pragma unroll
            for (int j = 0; j < 2; ++j)
                #pragma unroll
                for (int v = 0; v < 4; ++v)
                    red[fidx + i * 8 + j * 4 + v] = acc[i][j][v];
    }
    __syncthreads();
    if (kg == 0) {
        #pragma unroll
        for (int i = 0; i < 2; ++i)
            #pragma unroll
            for (int j = 0; j < 2; ++j) {
                const int col = col0 + wn * 32 + j * 16 + rl;
                const float bb = b2[col];
                #pragma unroll
                for (int v = 0; v < 4; ++v) {
                    const int row = row0 + wm * 32 + i * 16 + hi * 4 + v;
                    out[(size_t)row * O_ + col] =
                        acc[i][j][v] + red[fidx + i * 8 + j * 4 + v] + bb;
                }
            }
    }
}

// ---------------------------------------------------------------------------
extern "C" void kernel_launch(void* const* d_in, const int* in_sizes, int n_in,
                              void* d_out, int out_size, void* d_ws, size_t ws_size,
                              hipStream_t stream) {
    const float* x        = (const float*)d_in[0];
    const float* mask     = (const float*)d_in[1];
    const float* unpadded = (const float*)d_in[2];
    const float* W1       = (const float*)d_in[3];
    const float* b1       = (const float*)d_in[4];
    const float* W2       = (const float*)d_in[5];
    const float* b2       = (const float*)d_in[6];
    float* out = (float*)d_out;

    float* ws = (float*)d_ws;
    float* scale = ws;                        // 3072 f32
    ushort_t* bfw  = (ushort_t*)(ws + 4096);
    ushort_t* W1t  = bfw;                     // 2048*512
    ushort_t* W2t  = bfw + 1048576;           // 512*2048
    ushort_t* aggr = bfw + 2097152;           // 1024*512
    ushort_t* h    = bfw + 2621440;           // 3072*2048 bf16 (12 MB)

    k1_mega<<<2561, 256, 0, stream>>>(x, mask, W1, W2, unpadded,
                                      W1t, W2t, scale, aggr);
    gemm1_h<<<dim3(H_ / 64, M4 / 64), 256, 0, stream>>>(aggr, W1t, scale, b1, h);
    gemm2_pure<<<384, 512, 0, stream>>>(h, W2t, b2, out);
}